// Round 5
// baseline (582.662 us; speedup 1.0000x reference)
//
#include <hip/hip_runtime.h>
#include <hip/hip_bf16.h>

#define DEVINL __device__ __forceinline__

typedef __attribute__((ext_vector_type(4))) float f32x4;
typedef __attribute__((ext_vector_type(8))) short short8;

constexpr int CB = 2, CT = 2048, CD = 1024, CH = 16, CDK = 64;
constexpr int CM = CB * CT; // 4096 rows
constexpr float LOG2E = 1.44269504088896340736f;

DEVINL ushort f2bf(float f) {
  __hip_bfloat16 h = __float2bfloat16(f); // RNE
  ushort u; __builtin_memcpy(&u, &h, 2); return u;
}

// ---------------- fused f32 -> bf16 convert (all 6 tensors, one launch) ----------------
__global__ void cvt_all_kernel(const float* __restrict__ s0, ushort* __restrict__ d0, int n0,
                               const float* __restrict__ s1, ushort* __restrict__ d1, int n1,
                               const float* __restrict__ s2, ushort* __restrict__ d2, int n2,
                               const float* __restrict__ s3, ushort* __restrict__ d3, int n3,
                               const float* __restrict__ s4, ushort* __restrict__ d4, int n4,
                               const float* __restrict__ s5, ushort* __restrict__ d5, int n5)
{
  int i = (blockIdx.x * blockDim.x + threadIdx.x) * 4;
  const float* s; ushort* d;
  if (i < n0) { s = s0; d = d0; }
  else if ((i -= n0) < n1) { s = s1; d = d1; }
  else if ((i -= n1) < n2) { s = s2; d = d2; }
  else if ((i -= n2) < n3) { s = s3; d = d3; }
  else if ((i -= n3) < n4) { s = s4; d = d4; }
  else if ((i -= n4) < n5) { s = s5; d = d5; }
  else return;
  float4 v = *reinterpret_cast<const float4*>(s + i);
  ushort4 o;
  o.x = f2bf(v.x); o.y = f2bf(v.y); o.z = f2bf(v.z); o.w = f2bf(v.w);
  *reinterpret_cast<ushort4*>(d + i) = o;
}

// ---------------- mask -> per-64x64-tile all-valid flags ----------------
// flags[b*1024 + qb*32 + kb] = 1 iff every mask[b,0,qb*64+i,kb*64+j] != 0
__global__ void mask_flags_kernel(const int* __restrict__ mask, uint* __restrict__ flags) {
  const int tile = blockIdx.x;              // 2048 tiles
  const int b = tile >> 10, qb = (tile >> 5) & 31, kb = tile & 31;
  const int* base = mask + ((size_t)b * CT + qb * 64) * CT + kb * 64;
  const int r = threadIdx.x >> 2, c0 = (threadIdx.x & 3) * 16;
  int ok = 1;
  for (int j = 0; j < 4; ++j) {
    int4 v = *reinterpret_cast<const int4*>(base + (size_t)r * CT + c0 + j * 4);
    ok &= (v.x != 0) & (v.y != 0) & (v.z != 0) & (v.w != 0);
  }
  __shared__ int red[4];
  unsigned long long bal = __ballot(ok);
  if ((threadIdx.x & 63) == 0) red[threadIdx.x >> 6] = (bal == ~0ull);
  __syncthreads();
  if (threadIdx.x == 0) flags[tile] = (uint)(red[0] & red[1] & red[2] & red[3]);
}

// ---------------- NT GEMM (round-2 padded-LDS structure): C[i,j] = sum_k A[i,k]*Bm[j,k] ----
// mode 0: store bf16 to (B,H,T,DK); mode 1: store bf16 to (B,H,DK,T); mode 2: f32 row-major
__global__ __launch_bounds__(256, 2)
void gemm_nt_kernel(const ushort* __restrict__ A, const ushort* __restrict__ Bm,
                    const float* __restrict__ bias, void* __restrict__ Out,
                    int M, int N, int K, int mode, float scale)
{
  constexpr int BM = 128, BN = 128, BK = 32, LDT = 40; // pad 32->40: 2-way bank aliasing only
  __shared__ __align__(16) ushort As[BM * LDT];
  __shared__ __align__(16) ushort Bs[BN * LDT];
  const int tid = threadIdx.x;
  const int lane = tid & 63, wid = tid >> 6;
  const int wr = wid >> 1, wc = wid & 1;
  const int bm0 = blockIdx.y * BM, bn0 = blockIdx.x * BN;
  const int rsel = lane & 15, ksel = (lane >> 4) * 8;
  const int lrow = tid >> 2, lg = (tid & 3) * 8;

  f32x4 acc[4][4];
  for (int i = 0; i < 4; ++i) for (int j = 0; j < 4; ++j) acc[i][j] = f32x4{0.f, 0.f, 0.f, 0.f};

  for (int k0 = 0; k0 < K; k0 += BK) {
    __syncthreads();
    for (int p = 0; p < 2; ++p) {
      int r = p * 64 + lrow;
      *reinterpret_cast<short8*>(&As[r * LDT + lg]) =
          *reinterpret_cast<const short8*>(&A[(size_t)(bm0 + r) * K + k0 + lg]);
      *reinterpret_cast<short8*>(&Bs[r * LDT + lg]) =
          *reinterpret_cast<const short8*>(&Bm[(size_t)(bn0 + r) * K + k0 + lg]);
    }
    __syncthreads();
    short8 af[4], bfr[4];
    for (int mi = 0; mi < 4; ++mi)
      af[mi] = *reinterpret_cast<short8*>(&As[(wr * 64 + mi * 16 + rsel) * LDT + ksel]);
    for (int ni = 0; ni < 4; ++ni)
      bfr[ni] = *reinterpret_cast<short8*>(&Bs[(wc * 64 + ni * 16 + rsel) * LDT + ksel]);
    for (int mi = 0; mi < 4; ++mi)
      for (int ni = 0; ni < 4; ++ni)
        acc[mi][ni] = __builtin_amdgcn_mfma_f32_16x16x32_bf16(af[mi], bfr[ni], acc[mi][ni], 0, 0, 0);
  }

  const int r0 = (lane >> 4) * 4;
  for (int mi = 0; mi < 4; ++mi)
    for (int ni = 0; ni < 4; ++ni) {
      int gj = bn0 + wc * 64 + ni * 16 + rsel;
      float bv = bias[gj];
      for (int r = 0; r < 4; ++r) {
        int gi = bm0 + wr * 64 + mi * 16 + r0 + r;
        float v = (acc[mi][ni][r] + bv) * scale;
        if (mode == 2) {
          reinterpret_cast<float*>(Out)[(size_t)gi * N + gj] = v;
        } else {
          int bb = gi >> 11, t = gi & (CT - 1), h = gj >> 6, dk = gj & 63;
          size_t idx = (mode == 0)
              ? (((size_t)(bb * CH + h) * CT + t) * CDK + dk)
              : (((size_t)(bb * CH + h) * CDK + dk) * CT + t);
          reinterpret_cast<ushort*>(Out)[idx] = f2bf(v);
        }
      }
    }
}

// ---------------- fused attention (barrier-free: direct-global K/V fragments) ----------------
// grid: (T/64, B*H). 4 waves/block, each wave owns 16 q-rows, fully independent.
// Qb: (B,H,T,DK) bf16 with 0.125*log2e folded in. Kb: (B,H,T,DK). Vt: (B,H,DK,T).
// K-fragment read = 16 rows x 64 contiguous bytes per instruction -> coalesced from global;
// K/V panels (256 KB/head) stay L2-resident across the 32 q-blocks sharing them.
__global__ __launch_bounds__(256, 3)
void attn_kernel(const ushort* __restrict__ Qb, const ushort* __restrict__ Kb,
                 const ushort* __restrict__ Vt, const int* __restrict__ mask,
                 const uint* __restrict__ flags,
                 float* __restrict__ attn_out, ushort* __restrict__ oh)
{
  constexpr int KB = 64, LDK = 72; // P buffer row stride (2-way bank aliasing only)
  __shared__ __align__(16) ushort Ps[4][16 * LDK]; // per-wave P tile 16x64 (wave-private)

  const int tid = threadIdx.x, wid = tid >> 6, lane = tid & 63;
  const int bh = blockIdx.y, b = bh >> 4, h = bh & 15;
  const int qblk = blockIdx.x;
  const int q0 = qblk * 64 + wid * 16;
  const int rsel = lane & 15, grp = lane >> 4, ksel = grp * 8;
  const uint* fl = flags + (b << 10) + (qblk << 5);
  const ushort* kpan = Kb + (size_t)bh * CT * CDK;
  const ushort* vpan = Vt + (size_t)bh * CDK * CT;

  // Q fragments held in registers for the whole kernel (A-frag: i=lane&15, k=grp*8+r)
  short8 qa0, qa1;
  {
    const ushort* qrow = Qb + ((size_t)bh * CT + q0 + rsel) * CDK;
    qa0 = *reinterpret_cast<const short8*>(qrow + ksel);
    qa1 = *reinterpret_cast<const short8*>(qrow + 32 + ksel);
  }

  float l_part[4] = {0.f, 0.f, 0.f, 0.f};
  const int* mrow = mask + (size_t)b * CT * CT;

  // ---- pass 1: sum(exp2(s')) with fixed m=0 (per-lane partials, one reduce at end) ----
  for (int k0 = 0; k0 < CT; k0 += KB) {
    const uint f = fl[k0 >> 6];
    short8 kb0[4], kb1[4];
    for (int ni = 0; ni < 4; ++ni) {
      const ushort* krow = kpan + (size_t)(k0 + ni * 16 + rsel) * CDK;
      kb0[ni] = *reinterpret_cast<const short8*>(krow + ksel);
      kb1[ni] = *reinterpret_cast<const short8*>(krow + 32 + ksel);
    }
    for (int ni = 0; ni < 4; ++ni) {
      f32x4 z = {0.f, 0.f, 0.f, 0.f};
      z = __builtin_amdgcn_mfma_f32_16x16x32_bf16(qa0, kb0[ni], z, 0, 0, 0);
      z = __builtin_amdgcn_mfma_f32_16x16x32_bf16(qa1, kb1[ni], z, 0, 0, 0);
      if (f) {
        for (int r = 0; r < 4; ++r) l_part[r] += exp2f(z[r]);
      } else {
        int kk = k0 + ni * 16 + rsel;
        for (int r = 0; r < 4; ++r) {
          int q = q0 + grp * 4 + r;
          l_part[r] += mrow[(size_t)q * CT + kk] ? exp2f(z[r]) : 0.f;
        }
      }
    }
  }
  for (int off = 1; off < 16; off <<= 1)
    for (int r = 0; r < 4; ++r) l_part[r] += __shfl_xor(l_part[r], off, 64);
  float inv_l[4];
  for (int r = 0; r < 4; ++r) inv_l[r] = 1.f / l_part[r];

  f32x4 oacc[4];
  for (int nd = 0; nd < 4; ++nd) oacc[nd] = f32x4{0.f, 0.f, 0.f, 0.f};
  float* arow = attn_out + (size_t)bh * CT * CT;
  ushort* pw = &Ps[wid][0];

  // ---- pass 2: recompute scores, write attn, PV accumulate ----
  for (int k0 = 0; k0 < CT; k0 += KB) {
    const uint f = fl[k0 >> 6];
    short8 kb0[4], kb1[4];
    for (int ni = 0; ni < 4; ++ni) {
      const ushort* krow = kpan + (size_t)(k0 + ni * 16 + rsel) * CDK;
      kb0[ni] = *reinterpret_cast<const short8*>(krow + ksel);
      kb1[ni] = *reinterpret_cast<const short8*>(krow + 32 + ksel);
    }
    for (int ni = 0; ni < 4; ++ni) {
      f32x4 z = {0.f, 0.f, 0.f, 0.f};
      z = __builtin_amdgcn_mfma_f32_16x16x32_bf16(qa0, kb0[ni], z, 0, 0, 0);
      z = __builtin_amdgcn_mfma_f32_16x16x32_bf16(qa1, kb1[ni], z, 0, 0, 0);
      int kk = k0 + ni * 16 + rsel;
      for (int r = 0; r < 4; ++r) {
        int q = q0 + grp * 4 + r;
        float p;
        if (f) p = exp2f(z[r]);
        else   p = mrow[(size_t)q * CT + kk] ? exp2f(z[r]) : 0.f;
        arow[(size_t)q * CT + kk] = p * inv_l[r];
        pw[(grp * 4 + r) * LDK + ni * 16 + rsel] = f2bf(p); // wave-private LDS
      }
    }
    // re-fragment P (same-wave LDS round trip; compiler inserts lgkmcnt wait)
    short8 pa0 = *reinterpret_cast<short8*>(&pw[rsel * LDK + ksel]);
    short8 pa1 = *reinterpret_cast<short8*>(&pw[rsel * LDK + 32 + ksel]);
    for (int nd = 0; nd < 4; ++nd) {
      const ushort* vrow = vpan + (size_t)(nd * 16 + rsel) * CT + k0;
      short8 vb0 = *reinterpret_cast<const short8*>(vrow + ksel);
      short8 vb1 = *reinterpret_cast<const short8*>(vrow + 32 + ksel);
      oacc[nd] = __builtin_amdgcn_mfma_f32_16x16x32_bf16(pa0, vb0, oacc[nd], 0, 0, 0);
      oacc[nd] = __builtin_amdgcn_mfma_f32_16x16x32_bf16(pa1, vb1, oacc[nd], 0, 0, 0);
    }
  }

  // out_heads (B,T,D) bf16, normalized by 1/l
  for (int nd = 0; nd < 4; ++nd)
    for (int r = 0; r < 4; ++r) {
      int q = q0 + grp * 4 + r, d = nd * 16 + rsel;
      oh[((size_t)b * CT + q) * CD + h * CDK + d] = f2bf(oacc[nd][r] * inv_l[r]);
    }
}

// ---------------- launcher ----------------
extern "C" void kernel_launch(void* const* d_in, const int* in_sizes, int n_in,
                              void* d_out, int out_size, void* d_ws, size_t ws_size,
                              hipStream_t stream)
{
  const float* x_q  = (const float*)d_in[0];
  const float* x_kv = (const float*)d_in[1];
  const int*   mask = (const int*)d_in[2];
  const float* Wq = (const float*)d_in[3];
  const float* bq = (const float*)d_in[4];
  const float* Wk = (const float*)d_in[5];
  const float* bk = (const float*)d_in[6];
  const float* Wv = (const float*)d_in[7];
  const float* bv = (const float*)d_in[8];
  const float* Wo = (const float*)d_in[9];
  const float* bo = (const float*)d_in[10];

  float* out  = (float*)d_out;
  float* attn = out + (size_t)CB * CT * CD;

  char* w = (char*)d_ws;
  auto alloc = [&](size_t bytes) { char* p = w; w += (bytes + 255) & ~(size_t)255; return p; };
  ushort* xq_bf  = (ushort*)alloc((size_t)CM * CD * 2);
  ushort* xkv_bf = (ushort*)alloc((size_t)CM * CD * 2);
  ushort* Wq_bf  = (ushort*)alloc((size_t)CD * CD * 2);
  ushort* Wk_bf  = (ushort*)alloc((size_t)CD * CD * 2);
  ushort* Wv_bf  = (ushort*)alloc((size_t)CD * CD * 2);
  ushort* Wo_bf  = (ushort*)alloc((size_t)CD * CD * 2);
  ushort* Q_bf   = (ushort*)alloc((size_t)CM * CD * 2);
  ushort* K_bf   = (ushort*)alloc((size_t)CM * CD * 2);
  ushort* Vt_bf  = (ushort*)alloc((size_t)CM * CD * 2);
  ushort* oh_bf  = (ushort*)alloc((size_t)CM * CD * 2);
  uint*   mflags = (uint*)alloc(2048 * sizeof(uint));

  // one fused convert launch for all 6 f32->bf16 tensors
  {
    const int nx = CM * CD, nw = CD * CD;
    const int total_quads = (2 * nx + 4 * nw) / 4;
    const int blocks = (total_quads + 255) / 256;
    hipLaunchKernelGGL(cvt_all_kernel, dim3(blocks), dim3(256), 0, stream,
                       x_q, xq_bf, nx, x_kv, xkv_bf, nx,
                       Wq, Wq_bf, nw, Wk, Wk_bf, nw,
                       Wv, Wv_bf, nw, Wo, Wo_bf, nw);
  }

  hipLaunchKernelGGL(mask_flags_kernel, dim3(2048), dim3(256), 0, stream, mask, mflags);

  dim3 gproj(CD / 128, CM / 128); // (8, 32)
  // Q carries 1/sqrt(DK) * log2e so attn exponentials are exp2(s')
  hipLaunchKernelGGL(gemm_nt_kernel, gproj, dim3(256), 0, stream, xq_bf,  Wq_bf, bq, (void*)Q_bf,  CM, CD, CD, 0, 0.125f * LOG2E);
  hipLaunchKernelGGL(gemm_nt_kernel, gproj, dim3(256), 0, stream, xkv_bf, Wk_bf, bk, (void*)K_bf,  CM, CD, CD, 0, 1.0f);
  hipLaunchKernelGGL(gemm_nt_kernel, gproj, dim3(256), 0, stream, xkv_bf, Wv_bf, bv, (void*)Vt_bf, CM, CD, CD, 1, 1.0f);

  hipLaunchKernelGGL(attn_kernel, dim3(CT / 64, CB * CH), dim3(256), 0, stream,
                     Q_bf, K_bf, Vt_bf, mask, mflags, attn, oh_bf);

  hipLaunchKernelGGL(gemm_nt_kernel, gproj, dim3(256), 0, stream, oh_bf, Wo_bf, bo, d_out, CM, CD, CD, 2, 1.0f);
}

// Round 6
// 359.764 us; speedup vs baseline: 1.6196x; 1.6196x over previous
//
#include <hip/hip_runtime.h>
#include <hip/hip_bf16.h>

#define DEVINL __device__ __forceinline__

typedef __attribute__((ext_vector_type(4))) float f32x4;
typedef __attribute__((ext_vector_type(8))) short short8;

constexpr int CB = 2, CT = 2048, CD = 1024, CH = 16, CDK = 64;
constexpr int CM = CB * CT; // 4096 rows
constexpr float LOG2E = 1.44269504088896340736f;

DEVINL ushort f2bf(float f) {
  __hip_bfloat16 h = __float2bfloat16(f); // RNE
  ushort u; __builtin_memcpy(&u, &h, 2); return u;
}

// ---------------- fused f32 -> bf16 convert (all 6 tensors, one launch) ----------------
__global__ void cvt_all_kernel(const float* __restrict__ s0, ushort* __restrict__ d0, int n0,
                               const float* __restrict__ s1, ushort* __restrict__ d1, int n1,
                               const float* __restrict__ s2, ushort* __restrict__ d2, int n2,
                               const float* __restrict__ s3, ushort* __restrict__ d3, int n3,
                               const float* __restrict__ s4, ushort* __restrict__ d4, int n4,
                               const float* __restrict__ s5, ushort* __restrict__ d5, int n5)
{
  int i = (blockIdx.x * blockDim.x + threadIdx.x) * 4;
  const float* s; ushort* d;
  if (i < n0) { s = s0; d = d0; }
  else if ((i -= n0) < n1) { s = s1; d = d1; }
  else if ((i -= n1) < n2) { s = s2; d = d2; }
  else if ((i -= n2) < n3) { s = s3; d = d3; }
  else if ((i -= n3) < n4) { s = s4; d = d4; }
  else if ((i -= n4) < n5) { s = s5; d = d5; }
  else return;
  float4 v = *reinterpret_cast<const float4*>(s + i);
  ushort4 o;
  o.x = f2bf(v.x); o.y = f2bf(v.y); o.z = f2bf(v.z); o.w = f2bf(v.w);
  *reinterpret_cast<ushort4*>(d + i) = o;
}

// ---------------- mask -> per-64x64-tile all-valid flags ----------------
// flags[b*1024 + qb*32 + kb] = 1 iff every mask[b,0,qb*64+i,kb*64+j] != 0
__global__ void mask_flags_kernel(const int* __restrict__ mask, uint* __restrict__ flags) {
  const int tile = blockIdx.x;              // 2048 tiles
  const int b = tile >> 10, qb = (tile >> 5) & 31, kb = tile & 31;
  const int* base = mask + ((size_t)b * CT + qb * 64) * CT + kb * 64;
  const int r = threadIdx.x >> 2, c0 = (threadIdx.x & 3) * 16;
  int ok = 1;
  for (int j = 0; j < 4; ++j) {
    int4 v = *reinterpret_cast<const int4*>(base + (size_t)r * CT + c0 + j * 4);
    ok &= (v.x != 0) & (v.y != 0) & (v.z != 0) & (v.w != 0);
  }
  __shared__ int red[4];
  unsigned long long bal = __ballot(ok);
  if ((threadIdx.x & 63) == 0) red[threadIdx.x >> 6] = (bal == ~0ull);
  __syncthreads();
  if (threadIdx.x == 0) flags[tile] = (uint)(red[0] & red[1] & red[2] & red[3]);
}

// ---------------- NT GEMM (round-2 padded-LDS structure): C[i,j] = sum_k A[i,k]*Bm[j,k] ----
// mode 0: store bf16 to (B,H,T,DK); mode 1: store bf16 to (B,H,DK,T); mode 2: f32 row-major
__global__ __launch_bounds__(256, 2)
void gemm_nt_kernel(const ushort* __restrict__ A, const ushort* __restrict__ Bm,
                    const float* __restrict__ bias, void* __restrict__ Out,
                    int M, int N, int K, int mode, float scale)
{
  constexpr int BM = 128, BN = 128, BK = 32, LDT = 40; // pad 32->40: 2-way bank aliasing only
  __shared__ __align__(16) ushort As[BM * LDT];
  __shared__ __align__(16) ushort Bs[BN * LDT];
  const int tid = threadIdx.x;
  const int lane = tid & 63, wid = tid >> 6;
  const int wr = wid >> 1, wc = wid & 1;
  const int bm0 = blockIdx.y * BM, bn0 = blockIdx.x * BN;
  const int rsel = lane & 15, ksel = (lane >> 4) * 8;
  const int lrow = tid >> 2, lg = (tid & 3) * 8;

  f32x4 acc[4][4];
  for (int i = 0; i < 4; ++i) for (int j = 0; j < 4; ++j) acc[i][j] = f32x4{0.f, 0.f, 0.f, 0.f};

  for (int k0 = 0; k0 < K; k0 += BK) {
    __syncthreads();
    for (int p = 0; p < 2; ++p) {
      int r = p * 64 + lrow;
      *reinterpret_cast<short8*>(&As[r * LDT + lg]) =
          *reinterpret_cast<const short8*>(&A[(size_t)(bm0 + r) * K + k0 + lg]);
      *reinterpret_cast<short8*>(&Bs[r * LDT + lg]) =
          *reinterpret_cast<const short8*>(&Bm[(size_t)(bn0 + r) * K + k0 + lg]);
    }
    __syncthreads();
    short8 af[4], bfr[4];
    for (int mi = 0; mi < 4; ++mi)
      af[mi] = *reinterpret_cast<short8*>(&As[(wr * 64 + mi * 16 + rsel) * LDT + ksel]);
    for (int ni = 0; ni < 4; ++ni)
      bfr[ni] = *reinterpret_cast<short8*>(&Bs[(wc * 64 + ni * 16 + rsel) * LDT + ksel]);
    for (int mi = 0; mi < 4; ++mi)
      for (int ni = 0; ni < 4; ++ni)
        acc[mi][ni] = __builtin_amdgcn_mfma_f32_16x16x32_bf16(af[mi], bfr[ni], acc[mi][ni], 0, 0, 0);
  }

  const int r0 = (lane >> 4) * 4;
  for (int mi = 0; mi < 4; ++mi)
    for (int ni = 0; ni < 4; ++ni) {
      int gj = bn0 + wc * 64 + ni * 16 + rsel;
      float bv = bias[gj];
      for (int r = 0; r < 4; ++r) {
        int gi = bm0 + wr * 64 + mi * 16 + r0 + r;
        float v = (acc[mi][ni][r] + bv) * scale;
        if (mode == 2) {
          reinterpret_cast<float*>(Out)[(size_t)gi * N + gj] = v;
        } else {
          int bb = gi >> 11, t = gi & (CT - 1), h = gj >> 6, dk = gj & 63;
          size_t idx = (mode == 0)
              ? (((size_t)(bb * CH + h) * CT + t) * CDK + dk)
              : (((size_t)(bb * CH + h) * CDK + dk) * CT + t);
          reinterpret_cast<ushort*>(Out)[idx] = f2bf(v);
        }
      }
    }
}

// ---------------- fused attention (staged LDS, 8 waves / 128 q-rows per block) ----------------
// grid: (T/128, B*H). Each wave owns 16 q-rows; K/V tiles staged once per 128 q-rows.
// Qb: (B,H,T,DK) bf16 with 0.125*log2e folded in. Kb: (B,H,T,DK). Vt: (B,H,DK,T).
__global__ __launch_bounds__(512, 2)
void attn_kernel(const ushort* __restrict__ Qb, const ushort* __restrict__ Kb,
                 const ushort* __restrict__ Vt, const int* __restrict__ mask,
                 const uint* __restrict__ flags,
                 float* __restrict__ attn_out, ushort* __restrict__ oh)
{
  constexpr int KB = 64, LDK = 72; // pad 64->72 bf16 (144B rows): 2-way aliasing only
  __shared__ __align__(16) ushort Ks[KB * LDK];
  __shared__ __align__(16) ushort Vs[CDK * LDK];
  __shared__ __align__(16) ushort Ps[8][16 * LDK]; // per-wave P tile 16x64

  const int tid = threadIdx.x, wid = tid >> 6, lane = tid & 63;
  const int bh = blockIdx.y, b = bh >> 4, h = bh & 15;
  const int qblk = blockIdx.x;                 // 0..15 (128 q-rows each)
  const int q0 = qblk * 128 + wid * 16;
  const int rsel = lane & 15, grp = lane >> 4, ksel = grp * 8;
  const int srow = tid >> 3, scol = (tid & 7) * 8; // 512 threads stage 64x64 in one pass
  const uint* fl = flags + (b << 10) + ((q0 >> 6) << 5);

  // Q fragments held in registers for the whole kernel (A-frag: i=lane&15, k=grp*8+r)
  short8 qa0, qa1;
  {
    const ushort* qrow = Qb + ((size_t)bh * CT + q0 + rsel) * CDK;
    qa0 = *reinterpret_cast<const short8*>(qrow + ksel);
    qa1 = *reinterpret_cast<const short8*>(qrow + 32 + ksel);
  }

  float l_part[4] = {0.f, 0.f, 0.f, 0.f};
  const int* mrow = mask + (size_t)b * CT * CT;

  // ---- pass 1: sum(exp2(s')) with fixed m=0 (per-lane partials, one reduce at end) ----
  for (int k0 = 0; k0 < CT; k0 += KB) {
    __syncthreads();
    *reinterpret_cast<short8*>(&Ks[srow * LDK + scol]) =
        *reinterpret_cast<const short8*>(&Kb[((size_t)bh * CT + k0 + srow) * CDK + scol]);
    __syncthreads();
    const uint f = fl[k0 >> 6];
    for (int ni = 0; ni < 4; ++ni) {
      f32x4 z = {0.f, 0.f, 0.f, 0.f};
      short8 kb0 = *reinterpret_cast<short8*>(&Ks[(ni * 16 + rsel) * LDK + ksel]);
      short8 kb1 = *reinterpret_cast<short8*>(&Ks[(ni * 16 + rsel) * LDK + 32 + ksel]);
      z = __builtin_amdgcn_mfma_f32_16x16x32_bf16(qa0, kb0, z, 0, 0, 0);
      z = __builtin_amdgcn_mfma_f32_16x16x32_bf16(qa1, kb1, z, 0, 0, 0);
      if (f) {
        for (int r = 0; r < 4; ++r) l_part[r] += exp2f(z[r]);
      } else {
        int kk = k0 + ni * 16 + rsel;
        for (int r = 0; r < 4; ++r) {
          int q = q0 + grp * 4 + r;
          l_part[r] += mrow[(size_t)q * CT + kk] ? exp2f(z[r]) : 0.f;
        }
      }
    }
  }
  for (int off = 1; off < 16; off <<= 1)
    for (int r = 0; r < 4; ++r) l_part[r] += __shfl_xor(l_part[r], off, 64);
  float inv_l[4];
  for (int r = 0; r < 4; ++r) inv_l[r] = 1.f / l_part[r];

  f32x4 oacc[4];
  for (int nd = 0; nd < 4; ++nd) oacc[nd] = f32x4{0.f, 0.f, 0.f, 0.f};
  float* arow = attn_out + (size_t)bh * CT * CT;
  ushort* pw = &Ps[wid][0];

  // ---- pass 2: recompute scores, write attn, PV accumulate ----
  for (int k0 = 0; k0 < CT; k0 += KB) {
    __syncthreads();
    *reinterpret_cast<short8*>(&Ks[srow * LDK + scol]) =
        *reinterpret_cast<const short8*>(&Kb[((size_t)bh * CT + k0 + srow) * CDK + scol]);
    *reinterpret_cast<short8*>(&Vs[srow * LDK + scol]) =
        *reinterpret_cast<const short8*>(&Vt[((size_t)bh * CDK + srow) * CT + k0 + scol]);
    __syncthreads();
    const uint f = fl[k0 >> 6];
    for (int ni = 0; ni < 4; ++ni) {
      f32x4 z = {0.f, 0.f, 0.f, 0.f};
      short8 kb0 = *reinterpret_cast<short8*>(&Ks[(ni * 16 + rsel) * LDK + ksel]);
      short8 kb1 = *reinterpret_cast<short8*>(&Ks[(ni * 16 + rsel) * LDK + 32 + ksel]);
      z = __builtin_amdgcn_mfma_f32_16x16x32_bf16(qa0, kb0, z, 0, 0, 0);
      z = __builtin_amdgcn_mfma_f32_16x16x32_bf16(qa1, kb1, z, 0, 0, 0);
      int kk = k0 + ni * 16 + rsel;
      for (int r = 0; r < 4; ++r) {
        int q = q0 + grp * 4 + r;
        float p;
        if (f) p = exp2f(z[r]);
        else   p = mrow[(size_t)q * CT + kk] ? exp2f(z[r]) : 0.f;
        arow[(size_t)q * CT + kk] = p * inv_l[r];
        pw[(grp * 4 + r) * LDK + ni * 16 + rsel] = f2bf(p); // wave-private LDS
      }
    }
    short8 pa0 = *reinterpret_cast<short8*>(&pw[rsel * LDK + ksel]);
    short8 pa1 = *reinterpret_cast<short8*>(&pw[rsel * LDK + 32 + ksel]);
    for (int nd = 0; nd < 4; ++nd) {
      short8 vb0 = *reinterpret_cast<short8*>(&Vs[(nd * 16 + rsel) * LDK + ksel]);
      short8 vb1 = *reinterpret_cast<short8*>(&Vs[(nd * 16 + rsel) * LDK + 32 + ksel]);
      oacc[nd] = __builtin_amdgcn_mfma_f32_16x16x32_bf16(pa0, vb0, oacc[nd], 0, 0, 0);
      oacc[nd] = __builtin_amdgcn_mfma_f32_16x16x32_bf16(pa1, vb1, oacc[nd], 0, 0, 0);
    }
  }

  // out_heads (B,T,D) bf16, normalized by 1/l
  for (int nd = 0; nd < 4; ++nd)
    for (int r = 0; r < 4; ++r) {
      int q = q0 + grp * 4 + r, d = nd * 16 + rsel;
      oh[((size_t)b * CT + q) * CD + h * CDK + d] = f2bf(oacc[nd][r] * inv_l[r]);
    }
}

// ---------------- launcher ----------------
extern "C" void kernel_launch(void* const* d_in, const int* in_sizes, int n_in,
                              void* d_out, int out_size, void* d_ws, size_t ws_size,
                              hipStream_t stream)
{
  const float* x_q  = (const float*)d_in[0];
  const float* x_kv = (const float*)d_in[1];
  const int*   mask = (const int*)d_in[2];
  const float* Wq = (const float*)d_in[3];
  const float* bq = (const float*)d_in[4];
  const float* Wk = (const float*)d_in[5];
  const float* bk = (const float*)d_in[6];
  const float* Wv = (const float*)d_in[7];
  const float* bv = (const float*)d_in[8];
  const float* Wo = (const float*)d_in[9];
  const float* bo = (const float*)d_in[10];

  float* out  = (float*)d_out;
  float* attn = out + (size_t)CB * CT * CD;

  char* w = (char*)d_ws;
  auto alloc = [&](size_t bytes) { char* p = w; w += (bytes + 255) & ~(size_t)255; return p; };
  ushort* xq_bf  = (ushort*)alloc((size_t)CM * CD * 2);
  ushort* xkv_bf = (ushort*)alloc((size_t)CM * CD * 2);
  ushort* Wq_bf  = (ushort*)alloc((size_t)CD * CD * 2);
  ushort* Wk_bf  = (ushort*)alloc((size_t)CD * CD * 2);
  ushort* Wv_bf  = (ushort*)alloc((size_t)CD * CD * 2);
  ushort* Wo_bf  = (ushort*)alloc((size_t)CD * CD * 2);
  ushort* Q_bf   = (ushort*)alloc((size_t)CM * CD * 2);
  ushort* K_bf   = (ushort*)alloc((size_t)CM * CD * 2);
  ushort* Vt_bf  = (ushort*)alloc((size_t)CM * CD * 2);
  ushort* oh_bf  = (ushort*)alloc((size_t)CM * CD * 2);
  uint*   mflags = (uint*)alloc(2048 * sizeof(uint));

  // one fused convert launch for all 6 f32->bf16 tensors
  {
    const int nx = CM * CD, nw = CD * CD;
    const int total_quads = (2 * nx + 4 * nw) / 4;
    const int blocks = (total_quads + 255) / 256;
    hipLaunchKernelGGL(cvt_all_kernel, dim3(blocks), dim3(256), 0, stream,
                       x_q, xq_bf, nx, x_kv, xkv_bf, nx,
                       Wq, Wq_bf, nw, Wk, Wk_bf, nw,
                       Wv, Wv_bf, nw, Wo, Wo_bf, nw);
  }

  hipLaunchKernelGGL(mask_flags_kernel, dim3(2048), dim3(256), 0, stream, mask, mflags);

  dim3 gproj(CD / 128, CM / 128); // (8, 32)
  // Q carries 1/sqrt(DK) * log2e so attn exponentials are exp2(s')
  hipLaunchKernelGGL(gemm_nt_kernel, gproj, dim3(256), 0, stream, xq_bf,  Wq_bf, bq, (void*)Q_bf,  CM, CD, CD, 0, 0.125f * LOG2E);
  hipLaunchKernelGGL(gemm_nt_kernel, gproj, dim3(256), 0, stream, xkv_bf, Wk_bf, bk, (void*)K_bf,  CM, CD, CD, 0, 1.0f);
  hipLaunchKernelGGL(gemm_nt_kernel, gproj, dim3(256), 0, stream, xkv_bf, Wv_bf, bv, (void*)Vt_bf, CM, CD, CD, 1, 1.0f);

  hipLaunchKernelGGL(attn_kernel, dim3(CT / 128, CB * CH), dim3(512), 0, stream,
                     Q_bf, K_bf, Vt_bf, mask, mflags, attn, oh_bf);

  hipLaunchKernelGGL(gemm_nt_kernel, gproj, dim3(256), 0, stream, oh_bf, Wo_bf, bo, d_out, CM, CD, CD, 2, 1.0f);
}